// Round 6
// baseline (105.219 us; speedup 1.0000x reference)
//
#include <hip/hip_runtime.h>

// HybridSurvivalQ: quantum expval collapses to prod_{q=1..6} cos(x_q[q]+p[q])
// (CNOT ring => final bit0 = parity of bits 1..6; per-qubit E = cos(x+p)).
// Then MLP 65->32->16->1 with ReLU. fp32 vector ALU.
//
// R1: total includes ~81-88us harness reset (268MB fills x2 + small memsets).
// R2: NO runtime-indexed per-thread register arrays (scratch + replay bugs).
// R3 REGRESSION (113.6): full unroll + 22 upfront strided loads.
// R4 (105.1): rolled strided loop, kernel ~14-20us.
// R5 REGRESSION (125.6): 2-thr/row split; kernel measured 44.7us, latency-bound.
// R6 (105.0): block LDS staging == R4 total. Coalescing alone wasn't the cost;
//    stage->barrier->compute serializes (1-pass grid => phases align chip-wide)
//    and reg-staging pays a VGPR round-trip + full-drain __syncthreads.
// R7: wave-private K-pipelined staging, NO barriers (bench: infra failure,
//    "container failed twice" — same signature as R0 which passed on retry).
// R8 (this): R7 resubmit + one hardening: global_load_lds LDS-dest pointer
//    must be WAVE-UNIFORM (m104: HW writes base + lane*16 itself); R7 passed
//    a per-lane pointer (+lane*4 floats) — same final addresses if the
//    compiler readfirstlanes it, but outside the builtin's contract. Now the
//    uniform chunk base is passed and the HW lane offset lands each slot.
//    Structure recap:
//    - each wave owns 64 rows + private 16KB LDS (2 K-halves x 8 chunks);
//    - all 16 chunk-DMAs issued up front; s_waitcnt vmcnt(8) -> compute half0
//      UNDER half1's in-flight DMAs; vmcnt(0) -> compute half1 (T4 pattern);
//    - gll writes linearly, so conflict-minimal ds_read_b128 uses the
//      source-side swizzle (m173): slot s holds global colq (s&7)^(s>>3);
//      read lrow[k4 ^ (lane&7)] => 8 lanes per 4-bank window;
//    - x_q/qv first via direct loads so their waitcnt drains nothing of ours.

#define NQ 7
#define F  64
#define H1 32
#define H2 16

#define GLL16(GSRC, LDST)                                                    \
    __builtin_amdgcn_global_load_lds(                                        \
        (const __attribute__((address_space(1))) void*)(GSRC),               \
        (__attribute__((address_space(3))) void*)(LDST), 16, 0, 0)

// 128-FMA layer-1 sub-block: acc1 += outer(xv, W[4 consecutive rows])
#define L1_BODY(XV, WPTR)                                                    \
    do {                                                                     \
        const float* w_ = (WPTR);                                            \
        _Pragma("unroll")                                                    \
        for (int j = 0; j < H1; ++j) acc1[j] = fmaf((XV).x, w_[j],          acc1[j]); \
        _Pragma("unroll")                                                    \
        for (int j = 0; j < H1; ++j) acc1[j] = fmaf((XV).y, w_[H1 + j],     acc1[j]); \
        _Pragma("unroll")                                                    \
        for (int j = 0; j < H1; ++j) acc1[j] = fmaf((XV).z, w_[2 * H1 + j], acc1[j]); \
        _Pragma("unroll")                                                    \
        for (int j = 0; j < H1; ++j) acc1[j] = fmaf((XV).w, w_[3 * H1 + j], acc1[j]); \
    } while (0)

__global__ __launch_bounds__(256) void hybrid_fused(
    const float* __restrict__ x_q, const float* __restrict__ x_c,
    const float* __restrict__ q_params,
    const float* __restrict__ W1, const float* __restrict__ b1,
    const float* __restrict__ W2, const float* __restrict__ b2,
    const float* __restrict__ W3, const float* __restrict__ b3,
    float* __restrict__ out, int B)
{
    // 4 waves x 16KB wave-private region = 64KB -> 2 blocks/CU, 8 waves/CU.
    __shared__ __align__(16) float tile[4 * 4096];

    const int tid  = threadIdx.x;
    const int lane = tid & 63;
    const int w    = tid >> 6;
    const size_t blk_row0 = (size_t)blockIdx.x * 256;   // B = 512*256 exact
    const size_t row = blk_row0 + tid;                  // this thread's row

    // ---- x_q + quantum expectation FIRST (its waitcnt drains only itself) --
    float qv = 1.0f;
    #pragma unroll
    for (int q = 1; q < NQ; ++q)
        qv *= __cosf(x_q[row * NQ + q] + q_params[q]);

    // layer-1 init: k=0 row (qv) + bias   (scalar s_loads, lgkmcnt only)
    float acc1[H1];
    #pragma unroll
    for (int j = 0; j < H1; ++j)
        acc1[j] = fmaf(qv, W1[j], b1[j]);

    // ---- issue all 16 wave-chunk DMAs (half0 x8 then half1 x8) ----
    // chunk (h,c): lane s sources global (row = c*8 + (s>>3),
    // colq = h*8 + ((s&7)^(s>>3))); HW writes LDS chunkbase + s*16B.
    const int s_hi = lane >> 3;            // row-in-chunk
    const int s_lo = lane & 7;
    const int cqx  = s_lo ^ s_hi;          // source-swizzled colq within half
    const float* gbase = x_c + (blk_row0 + (size_t)w * 64 + s_hi) * F + cqx * 4;
    float* lbase = tile + w * 4096;        // floats; wave region = 1024 float4

    #pragma unroll
    for (int h = 0; h < 2; ++h)
        #pragma unroll
        for (int c = 0; c < 8; ++c)
            GLL16(gbase + (size_t)c * 8 * F + h * 32,
                  lbase + h * 2048 + c * 256);   // WAVE-UNIFORM dest base

    // ---- half 0: features 0..31, computed under half1's in-flight DMAs ----
    asm volatile("s_waitcnt vmcnt(8)" ::: "memory");
    const float4* lrow = reinterpret_cast<const float4*>(lbase)
                         + s_hi * 64 + s_lo * 8;   // +(k4^s_lo) selects colq k4
    #pragma unroll 1
    for (int k4 = 0; k4 < 8; ++k4) {
        const float4 xv = lrow[k4 ^ s_lo];                 // conflict-minimal
        L1_BODY(xv, W1 + (size_t)(1 + 4 * k4) * H1);       // uniform s_load
    }

    // ---- half 1: features 32..63 ----
    asm volatile("s_waitcnt vmcnt(0)" ::: "memory");
    #pragma unroll 1
    for (int k4 = 0; k4 < 8; ++k4) {
        const float4 xv = lrow[512 + (k4 ^ s_lo)];
        L1_BODY(xv, W1 + (size_t)(1 + 32 + 4 * k4) * H1);
    }

    // ---- layer 2: relu(acc1)(32) @ W2(32x16) + b2 (fully unrolled) ----
    float acc2[H2];
    #pragma unroll
    for (int j = 0; j < H2; ++j) acc2[j] = b2[j];
    #pragma unroll
    for (int k = 0; k < H1; ++k) {
        const float h = fmaxf(acc1[k], 0.0f);
        #pragma unroll
        for (int j = 0; j < H2; ++j)
            acc2[j] = fmaf(h, W2[k * H2 + j], acc2[j]);
    }

    // ---- layer 3: relu(acc2)(16) @ W3(16x1) + b3 ----
    float o = b3[0];
    #pragma unroll
    for (int k = 0; k < H2; ++k)
        o = fmaf(fmaxf(acc2[k], 0.0f), W3[k], o);

    out[row] = o;   // coalesced
}

extern "C" void kernel_launch(void* const* d_in, const int* in_sizes, int n_in,
                              void* d_out, int out_size, void* d_ws, size_t ws_size,
                              hipStream_t stream) {
    const float* x_q      = (const float*)d_in[0];
    const float* x_c      = (const float*)d_in[1];
    const float* q_params = (const float*)d_in[2];
    const float* W1       = (const float*)d_in[3];
    const float* b1       = (const float*)d_in[4];
    const float* W2       = (const float*)d_in[5];
    const float* b2       = (const float*)d_in[6];
    const float* W3       = (const float*)d_in[7];
    const float* b3       = (const float*)d_in[8];
    float* out = (float*)d_out;

    const int B = in_sizes[0] / NQ;        // 131072
    const int grid = (B + 255) / 256;      // 512 blocks of 256, exact

    hybrid_fused<<<grid, 256, 0, stream>>>(x_q, x_c, q_params,
                                           W1, b1, W2, b2, W3, b3,
                                           out, B);
}